// Round 8
// baseline (318.906 us; speedup 1.0000x reference)
//
#include <hip/hip_runtime.h>

// WeightedEmbedding: out[b,s,d] = sum_v x[b,s,v] * W[v,d]
// GEMM M=B*S=8192, K=V=4096, N=D=32, fp32.
//
// Round-6: occupancy attack. r3-r5 sat at 16 waves/CU (4/SIMD) with VALUBusy
// ~23% — all waves co-stalled. To reach 32 waves/CU, VGPR must be <=64
// (m69: occupancy halves at 64/128/256), so shrink the wave tile:
//   WM=4 rows (acc 16 VGPR), KV=32 (W ping-pong wrA/wrB = 32 VGPR).
// Grid = 2048 blocks x 4 waves = 8 blocks/CU = 32 waves/CU.
// x staged via async global_load_lds (1KB granule = 2 chunks, 4-buffer ring);
// uniform counted s_waitcnt vmcnt(5) — never drains the prefetch queue.

typedef float f32x4 __attribute__((ext_vector_type(4)));

constexpr int V      = 4096;   // vocab (K)
constexpr int D      = 32;     // embed dim (N)
constexpr int KV     = 32;     // v per compute chunk
constexpr int WM     = 4;      // rows per block
constexpr int KWAVES = 4;      // waves per block = K-split
constexpr int KQ     = V / KWAVES;     // 1024
constexpr int NCHUNK = KQ / KV;        // 32 compute chunks
constexpr int NBUF   = 4;              // super-buffers (1KB each = 2 chunks)

#define FMA4(A, S, W4) \
  do { (A).x = fmaf((S), (W4).x, (A).x); \
       (A).y = fmaf((S), (W4).y, (A).y); \
       (A).z = fmaf((S), (W4).z, (A).z); \
       (A).w = fmaf((S), (W4).w, (A).w); } while (0)

__global__ __launch_bounds__(256, 8)
void WeightedEmbedding_48249662603573_kernel(const float* __restrict__ x,
                                             const float* __restrict__ w,
                                             float* __restrict__ out,
                                             int M) {
  __shared__ float xs[KWAVES][NBUF][WM][64];   // 16 KB (1KB per super-buffer)
  __shared__ f32x4 red[KWAVES][WM][8];         // 2 KB

  const int tid  = threadIdx.x;
  const int kq   = tid >> 6;   // wave id = K-quarter (wave-uniform)
  const int lane = tid & 63;
  const int d4   = lane & 7;   // owns d = d4*4 .. +3
  const int h    = lane >> 3;  // v-phase: v = v0 + h*4 .. +3 (per chunk)
  const int r0   = blockIdx.x * WM;
  const int k0   = kq * KQ;

  // Staging source: lane i -> row r0 + i/16, cols (i%16)*4..+3 of the
  // 64-v super-chunk. One 1KB global_load_lds per super-chunk.
  const float* gsrc  = x + (size_t)(r0 + (lane >> 4)) * V + k0 + (lane & 15) * 4;
  const float* wbase = w + (size_t)(k0 + h * 4) * D + d4 * 4;

  // stage super-chunk ss (64 v = chunks 2ss, 2ss+1); mask-wrap is harmless
  #define STAGE(ss)                                                           \
    do {                                                                      \
      const int b_ = (ss) & (NBUF - 1);                                       \
      const float* s_ = gsrc + (size_t)(((ss) & (NCHUNK / 2 - 1)) * 64);      \
      __builtin_amdgcn_global_load_lds(                                       \
          (const __attribute__((address_space(1))) void*)s_,                  \
          (__attribute__((address_space(3))) void*)&xs[kq][b_][0][0],         \
          16, 0, 0);                                                          \
    } while (0)

  // 4 independent strided f32x4 loads of W chunk cc into named array DST
  #define LOADW(DST, cc)                                                      \
    do {                                                                      \
      const float* wp_ = wbase + (size_t)(((cc) & (NCHUNK - 1)) * KV) * D;    \
      _Pragma("unroll")                                                       \
      for (int j = 0; j < 4; ++j)                                             \
        DST[j] = *(const f32x4*)(wp_ + (size_t)j * D);                        \
    } while (0)

  // exactly 5 VMEM ops are younger than W(c) at every wait point:
  //   even iter: W(c+1)[4] + S[1];  odd iter: S[1] + W(c+1)[4].
  // So vmcnt(5) proves W(c) and S(c/2) retired, prefetches stay in flight.
  #define WAIT5() asm volatile("s_waitcnt vmcnt(5)" ::: "memory")

  #define COMPUTE(cc, WR)                                                     \
    do {                                                                      \
      const float* xp_ = &xs[kq][((cc) >> 1) & (NBUF - 1)][0][0]              \
                         + ((cc) & 1) * 32 + h * 4;                           \
      _Pragma("unroll")                                                       \
      for (int m = 0; m < WM; ++m) {                                          \
        f32x4 x4 = *(const f32x4*)(xp_ + m * 64);                             \
        FMA4(acc[m], x4.x, WR[0]);                                            \
        FMA4(acc[m], x4.y, WR[1]);                                            \
        FMA4(acc[m], x4.z, WR[2]);                                            \
        FMA4(acc[m], x4.w, WR[3]);                                            \
      }                                                                       \
    } while (0)

  f32x4 acc[WM];
#pragma unroll
  for (int m = 0; m < WM; ++m) acc[m] = (f32x4)(0.f);

  f32x4 wrE[4], wrO[4];

  // prologue: queue = S0, S1, W0(4)
  STAGE(0);
  STAGE(1);
  LOADW(wrE, 0);

  for (int c = 0; c < NCHUNK; c += 2) {
    // even chunk: compute wrE
    LOADW(wrO, c + 1);          // W(c+1)
    STAGE((c >> 1) + 2);        // S(s+2)
    WAIT5();                    // W(c), S(s) retired; 5 in flight
    COMPUTE(c, wrE);

    // odd chunk: compute wrO
    LOADW(wrE, c + 2);          // W(c+2) (wraps harmlessly at tail)
    WAIT5();                    // W(c+1) retired
    COMPUTE(c + 1, wrO);
  }

  // --- butterfly reduce across the 8 v-phase lanes (lane bits 3..5)
#pragma unroll
  for (int off = 8; off <= 32; off <<= 1) {
#pragma unroll
    for (int m = 0; m < WM; ++m) {
      acc[m].x += __shfl_xor(acc[m].x, off, 64);
      acc[m].y += __shfl_xor(acc[m].y, off, 64);
      acc[m].z += __shfl_xor(acc[m].z, off, 64);
      acc[m].w += __shfl_xor(acc[m].w, off, 64);
    }
  }

  // all 8 h-lanes now hold identical sums; lanes h<4 write row h (static pick)
  f32x4 res = acc[0];
#pragma unroll
  for (int m = 1; m < WM; ++m)
    if ((h & 3) == m) res = acc[m];
  if (h < WM) red[kq][h & 3][d4] = res;

  __syncthreads();   // also drains any in-flight wrap stages

  // --- cross-wave (K-quarter) reduce: 128 outputs per block
  if (tid < WM * D) {
    const int row = tid >> 5;      // 0..3
    const int d   = tid & 31;      // 0..31
    const float* rf = (const float*)red;
    const int idx = row * D + d;   // within one kq slice (128 floats)
    float s = rf[idx] + rf[128 + idx] + rf[256 + idx] + rf[384 + idx];
    if (r0 + row < M)
      out[(size_t)(r0 + row) * D + d] = s;
  }
}

extern "C" void kernel_launch(void* const* d_in, const int* in_sizes, int n_in,
                              void* d_out, int out_size, void* d_ws, size_t ws_size,
                              hipStream_t stream) {
  const float* x = (const float*)d_in[0];
  const float* w = (const float*)d_in[1];
  float* out = (float*)d_out;

  const int M = in_sizes[0] / V;           // 8192
  dim3 grid((M + WM - 1) / WM);            // 2048 blocks = 8 blocks/CU
  dim3 block(KWAVES * 64);                 // 256 threads = 4 waves
  hipLaunchKernelGGL(WeightedEmbedding_48249662603573_kernel,
                     grid, block, 0, stream, x, w, out, M);
}

// Round 9
// 234.528 us; speedup vs baseline: 1.3598x; 1.3598x over previous
//
#include <hip/hip_runtime.h>

// WeightedEmbedding: out[b,s,d] = sum_v x[b,s,v] * W[v,d]
// GEMM M=B*S=8192, K=V=4096, N=D=32, fp32.
//
// Round-9: r8's launch_bounds(256,8) + ~64-VGPR need caused a spill
// catastrophe (VGPR=32, WRITE_SIZE=165MB of scratch). Keep 32 waves/CU but
// cut register need to ~48: SINGLE-buffered W (wr[4]=16 VGPR) + acc 16.
// TLP (8 waves/SIMD) hides W's L2 latency and the partial stage drains —
// no source pipelining for W at all.
// vmcnt ledger (in-order retirement; survivors are the YOUNGEST ops):
//   even chunk: LOADW[4]; STAGE[1]; vmcnt(1)  (stage survives, LW proven)
//   odd  chunk: LOADW[4];            vmcnt(0)  (youngest is LW -> full wait)

typedef float f32x4 __attribute__((ext_vector_type(4)));

constexpr int V      = 4096;   // vocab (K)
constexpr int D      = 32;     // embed dim (N)
constexpr int KV     = 32;     // v per compute chunk
constexpr int WM     = 4;      // rows per block
constexpr int KWAVES = 4;      // waves per block = K-split
constexpr int KQ     = V / KWAVES;     // 1024
constexpr int NCHUNK = KQ / KV;        // 32 compute chunks
constexpr int NBUF   = 4;              // super-buffers (1KB each = 2 chunks)

#define FMA4(A, S, W4) \
  do { (A).x = fmaf((S), (W4).x, (A).x); \
       (A).y = fmaf((S), (W4).y, (A).y); \
       (A).z = fmaf((S), (W4).z, (A).z); \
       (A).w = fmaf((S), (W4).w, (A).w); } while (0)

__global__ __launch_bounds__(256, 8)
void WeightedEmbedding_48249662603573_kernel(const float* __restrict__ x,
                                             const float* __restrict__ w,
                                             float* __restrict__ out,
                                             int M) {
  __shared__ float xs[KWAVES][NBUF][WM][64];   // 16 KB (1KB per super-buffer)
  __shared__ f32x4 red[KWAVES][WM][8];         // 2 KB

  const int tid  = threadIdx.x;
  const int kq   = tid >> 6;   // wave id = K-quarter (wave-uniform)
  const int lane = tid & 63;
  const int d4   = lane & 7;   // owns d = d4*4 .. +3
  const int h    = lane >> 3;  // v-phase: v = v0 + h*4 .. +3 (per chunk)
  const int r0   = blockIdx.x * WM;
  const int k0   = kq * KQ;

  // Staging source: lane i -> row r0 + i/16, cols (i%16)*4..+3 of the
  // 64-v super-chunk. One 1KB global_load_lds per super-chunk.
  const float* gsrc  = x + (size_t)(r0 + (lane >> 4)) * V + k0 + (lane & 15) * 4;
  const float* wbase = w + (size_t)(k0 + h * 4) * D + d4 * 4;

  // stage super-chunk ss (64 v = chunks 2ss, 2ss+1); mask-wrap is harmless
  #define STAGE(ss)                                                           \
    do {                                                                      \
      const int b_ = (ss) & (NBUF - 1);                                       \
      const float* s_ = gsrc + (size_t)(((ss) & (NCHUNK / 2 - 1)) * 64);      \
      __builtin_amdgcn_global_load_lds(                                       \
          (const __attribute__((address_space(1))) void*)s_,                  \
          (__attribute__((address_space(3))) void*)&xs[kq][b_][0][0],         \
          16, 0, 0);                                                          \
    } while (0)

  // 4 independent strided f32x4 loads of W chunk cc into wr
  #define LOADW(cc)                                                           \
    do {                                                                      \
      const float* wp_ = wbase + (size_t)(((cc) & (NCHUNK - 1)) * KV) * D;    \
      _Pragma("unroll")                                                       \
      for (int j = 0; j < 4; ++j)                                             \
        wr[j] = *(const f32x4*)(wp_ + (size_t)j * D);                         \
    } while (0)

  #define COMPUTE(cc)                                                         \
    do {                                                                      \
      const float* xp_ = &xs[kq][((cc) >> 1) & (NBUF - 1)][0][0]              \
                         + ((cc) & 1) * 32 + h * 4;                           \
      _Pragma("unroll")                                                       \
      for (int m = 0; m < WM; ++m) {                                          \
        f32x4 x4 = *(const f32x4*)(xp_ + m * 64);                             \
        FMA4(acc[m], x4.x, wr[0]);                                            \
        FMA4(acc[m], x4.y, wr[1]);                                            \
        FMA4(acc[m], x4.z, wr[2]);                                            \
        FMA4(acc[m], x4.w, wr[3]);                                            \
      }                                                                       \
    } while (0)

  f32x4 acc[WM];
#pragma unroll
  for (int m = 0; m < WM; ++m) acc[m] = (f32x4)(0.f);

  f32x4 wr[4];

  // prologue: queue = S0, S1
  STAGE(0);
  STAGE(1);

  for (int c = 0; c < NCHUNK; c += 2) {
    // even chunk
    LOADW(c);                   // [4 ops]
    STAGE((c >> 1) + 2);        // [1 op] -> youngest
    asm volatile("s_waitcnt vmcnt(1)" ::: "memory");  // LW(c)+older stages done
    COMPUTE(c);

    // odd chunk
    LOADW(c + 1);               // [4 ops] -> youngest
    asm volatile("s_waitcnt vmcnt(0)" ::: "memory");  // must fully drain
    COMPUTE(c + 1);
  }

  // --- butterfly reduce across the 8 v-phase lanes (lane bits 3..5)
#pragma unroll
  for (int off = 8; off <= 32; off <<= 1) {
#pragma unroll
    for (int m = 0; m < WM; ++m) {
      acc[m].x += __shfl_xor(acc[m].x, off, 64);
      acc[m].y += __shfl_xor(acc[m].y, off, 64);
      acc[m].z += __shfl_xor(acc[m].z, off, 64);
      acc[m].w += __shfl_xor(acc[m].w, off, 64);
    }
  }

  // all 8 h-lanes hold identical sums; static pick (rule #20), h<4 writes row h
  f32x4 res = acc[0];
#pragma unroll
  for (int m = 1; m < WM; ++m)
    if ((h & 3) == m) res = acc[m];
  if (h < WM) red[kq][h & 3][d4] = res;

  __syncthreads();

  // --- cross-wave (K-quarter) reduce: 128 outputs per block
  if (tid < WM * D) {
    const int row = tid >> 5;      // 0..3
    const int d   = tid & 31;      // 0..31
    const float* rf = (const float*)red;
    const int idx = row * D + d;   // within one kq slice (128 floats)
    float s = rf[idx] + rf[128 + idx] + rf[256 + idx] + rf[384 + idx];
    if (r0 + row < M)
      out[(size_t)(r0 + row) * D + d] = s;
  }
}

extern "C" void kernel_launch(void* const* d_in, const int* in_sizes, int n_in,
                              void* d_out, int out_size, void* d_ws, size_t ws_size,
                              hipStream_t stream) {
  const float* x = (const float*)d_in[0];
  const float* w = (const float*)d_in[1];
  float* out = (float*)d_out;

  const int M = in_sizes[0] / V;           // 8192
  dim3 grid((M + WM - 1) / WM);            // 2048 blocks = 8 blocks/CU
  dim3 block(KWAVES * 64);                 // 256 threads = 4 waves
  hipLaunchKernelGGL(WeightedEmbedding_48249662603573_kernel,
                     grid, block, 0, stream, x, w, out, M);
}